// Round 13
// baseline (410.603 us; speedup 1.0000x reference)
//
#include <hip/hip_runtime.h>
#include <math.h>

#define BB   4096
#define KK   200
#define DD   128
#define FDIM 1024
#define MASK_FILL (-4294967295.0f)   // -(2^32)+1, as fp32
#define NPROD 512                    // producer blocks (8 tgt rows each)

typedef float fx4 __attribute__((ext_vector_type(4)));

__device__ __forceinline__ float red32(float v) {
    #pragma unroll
    for (int off = 16; off > 0; off >>= 1) v += __shfl_xor(v, off);
    return v;
}

// One kernel. Blocks 0..NPROD-1 first compute tgt rows (producer phase), then
// ALL 2048 blocks run the R12 streaming attention for their 2 batch rows,
// gated per-block on a device-scope flag. Producer gemm overlaps consumer
// HBM streaming instead of serializing in front of it.
__global__ __launch_bounds__(256, 8) void fused(const float* __restrict__ tf,
                                                const float* __restrict__ nf,
                                                const float* __restrict__ nl,
                                                const int*   __restrict__ mask,
                                                const float* __restrict__ W,
                                                float* __restrict__ tgt,
                                                int*   __restrict__ flags,
                                                float* __restrict__ out) {
    __shared__ float s_red[8][DD];       // producer h-reduce (4 KiB)
    __shared__ float s_m[2][2], s_s[2][2];
    __shared__ fx4   s_an[2][2][32];
    __shared__ fx4   s_al[2][2][32];

    const int tid = threadIdx.x;
    const int bid = blockIdx.x;

    // ---- producer phase (blocks 0..511): tgt rows 8*bid..8*bid+7.
    // No LDS staging: t is a wave-broadcast global read (L2-resident tf block).
    if (bid < NPROD) {
        const int d = tid & 127;
        const int h = tid >> 7;          // 0/1: FD half (wave-uniform)
        const size_t r0 = (size_t)bid * 8;
        const fx4* wr  = (const fx4*)(W + (size_t)d * FDIM) + h * (FDIM / 8);
        const fx4* tf4 = (const fx4*)(tf + r0 * FDIM) + h * (FDIM / 8);
        float acc[8] = {0, 0, 0, 0, 0, 0, 0, 0};
        #pragma unroll 4
        for (int i = 0; i < FDIM / 8; ++i) {
            const fx4 w = wr[i];
            #pragma unroll
            for (int r = 0; r < 8; ++r) {
                const fx4 t = tf4[r * (FDIM / 4) + i];   // same addr across lanes
                acc[r] += w.x * t.x + w.y * t.y + w.z * t.z + w.w * t.w;
            }
        }
        if (h == 1) {
            #pragma unroll
            for (int r = 0; r < 8; ++r) s_red[r][d] = acc[r];
        }
        __syncthreads();
        if (h == 0) {
            #pragma unroll
            for (int r = 0; r < 8; ++r)
                tgt[(r0 + r) * DD + d] = acc[r] + s_red[r][d];
        }
        __syncthreads();                 // all writes done before publish
        if (tid == 0)
            __hip_atomic_store(flags + bid, 1, __ATOMIC_RELEASE, __HIP_MEMORY_SCOPE_AGENT);
    }

    // ---- consumer roles (all blocks)
    const int lane = tid & 63;
    const int l32  = lane & 31;          // fx4 column (d = 4*l32)
    const int h2   = (lane >> 5) & 1;    // parity half: 0 -> even k, 1 -> odd k
    const int bloc = tid >> 7;           // which of the block's 2 batch rows
    const int b    = __builtin_amdgcn_readfirstlane(bid * 2 + bloc);
    const int kw   = __builtin_amdgcn_readfirstlane((tid >> 6) & 1);  // k-range half

    const fx4* nf4 = (const fx4*)(nf + (size_t)b * KK * DD) + (size_t)kw * 50 * 64;
    const fx4* nl4 = (const fx4*)(nl + (size_t)b * KK * DD) + (size_t)kw * 50 * 64;
    const int* mb  = mask + (size_t)b * KK + kw * 100;

#define LOADC(N0, N1, L0, L1, c)                                    \
    {                                                               \
        const int base_ = (c) * 128 + lane;                         \
        N0 = __builtin_nontemporal_load(nf4 + base_);               \
        N1 = __builtin_nontemporal_load(nf4 + base_ + 64);          \
        L0 = __builtin_nontemporal_load(nl4 + base_);               \
        L1 = __builtin_nontemporal_load(nl4 + base_ + 64);          \
    }

#define COMPC(N0, N1, L0, L1, c)                                             \
    {                                                                        \
        float a0 = red32(N0.x * tg.x + N0.y * tg.y + N0.z * tg.z + N0.w * tg.w); \
        float a1 = red32(N1.x * tg.x + N1.y * tg.y + N1.z * tg.z + N1.w * tg.w); \
        const int k0_ = (c) * 4;                                             \
        const int mA_ = h2 ? mb[k0_ + 1] : mb[k0_];                          \
        const int mB_ = h2 ? mb[k0_ + 3] : mb[k0_ + 2];                      \
        a0 = (mA_ > 0) ? a0 : MASK_FILL;                                     \
        a1 = (mB_ > 0) ? a1 : MASK_FILL;                                     \
        const float mn_ = fmaxf(m, fmaxf(a0, a1));                           \
        const float r_  = __expf(m - mn_);                                   \
        m = mn_;                                                             \
        s *= r_; an *= r_; al *= r_;                                         \
        const float p0_ = __expf(a0 - m);                                    \
        const float p1_ = __expf(a1 - m);                                    \
        s += p0_ + p1_;                                                      \
        an += p0_ * N0 + p1_ * N1;                                           \
        al += p0_ * L0 + p1_ * L1;                                           \
    }

    // issue chunk-0 loads BEFORE the gate: input streams don't depend on tgt
    fx4 nA0, nA1, lA0, lA1, nB0, nB1, lB0, lB1;
    LOADC(nA0, nA1, lA0, lA1, 0)

    // ---- gate: wait for this block's tgt rows (relaxed spin, one acquire)
    if (tid == 0) {
        while (__hip_atomic_load(flags + (b >> 3), __ATOMIC_RELAXED,
                                 __HIP_MEMORY_SCOPE_AGENT) == 0)
            __builtin_amdgcn_s_sleep(8);
    }
    __syncthreads();
    __builtin_amdgcn_fence(__ATOMIC_ACQUIRE, "agent");
    __builtin_amdgcn_sched_barrier(0);   // keep the tgt load below the fence

    const fx4 tg = ((const fx4*)(tgt + (size_t)b * DD))[l32];

    float m = -INFINITY, s = 0.0f;
    fx4 an = {0, 0, 0, 0}, al = {0, 0, 0, 0};

    for (int c = 0; c < 24; c += 2) {
        LOADC(nB0, nB1, lB0, lB1, c + 1)
        COMPC(nA0, nA1, lA0, lA1, c)
        LOADC(nA0, nA1, lA0, lA1, c + 2)
        COMPC(nB0, nB1, lB0, lB1, c + 1)
    }
    COMPC(nA0, nA1, lA0, lA1, 24)

#undef LOADC
#undef COMPC

    // ---- intra-wave merge: even-k <-> odd-k halves
    {
        const float mo = __shfl_xor(m, 32);
        const float so = __shfl_xor(s, 32);
        fx4 ano, alo;
        ano.x = __shfl_xor(an.x, 32); ano.y = __shfl_xor(an.y, 32);
        ano.z = __shfl_xor(an.z, 32); ano.w = __shfl_xor(an.w, 32);
        alo.x = __shfl_xor(al.x, 32); alo.y = __shfl_xor(al.y, 32);
        alo.z = __shfl_xor(al.z, 32); alo.w = __shfl_xor(al.w, 32);
        const float mt = fmaxf(m, mo);
        const float e0 = __expf(m - mt);
        const float e1 = __expf(mo - mt);
        s  = s * e0 + so * e1;
        an = an * e0 + ano * e1;
        al = al * e0 + alo * e1;
        m  = mt;
    }

    // ---- cross-wave merge (k-range halves) via LDS, one barrier
    if (h2 == 0) s_an[bloc][kw][l32] = an; else s_al[bloc][kw][l32] = al;
    if (lane == 0) { s_m[bloc][kw] = m; s_s[bloc][kw] = s; }
    __syncthreads();

    if (kw == 0) {
        const float m1 = s_m[bloc][1];
        const float s1 = s_s[bloc][1];
        const fx4 mine  = (h2 == 0) ? an : al;
        const fx4 other = (h2 == 0) ? s_an[bloc][1][l32] : s_al[bloc][1][l32];
        const float M   = fmaxf(m, m1);
        const float e0  = __expf(m - M);
        const float e1  = __expf(m1 - M);
        const float inv = 1.0f / (s * e0 + s1 * e1);
        const fx4 r = (mine * e0 + other * e1) * inv;
        if (h2 == 0)
            __builtin_nontemporal_store(r, &((fx4*)(out + (size_t)b * DD))[l32]);
        else
            __builtin_nontemporal_store(r, &((fx4*)(out + (size_t)BB * DD + (size_t)b * DD))[l32]);
    }
}

extern "C" void kernel_launch(void* const* d_in, const int* in_sizes, int n_in,
                              void* d_out, int out_size, void* d_ws, size_t ws_size,
                              hipStream_t stream) {
    const float* tf   = (const float*)d_in[0];
    const float* nf   = (const float*)d_in[1];
    const float* nl   = (const float*)d_in[2];
    const int*   mask = (const int*)d_in[3];
    const float* W    = (const float*)d_in[4];
    float* out   = (float*)d_out;
    float* tgt   = (float*)d_ws;                               // 2 MiB
    int*   flags = (int*)((char*)d_ws + 2 * 1024 * 1024);      // 2 KiB

    hipMemsetAsync(flags, 0, NPROD * sizeof(int), stream);     // deterministic gate
    fused<<<BB / 2, 256, 0, stream>>>(tf, nf, nl, mask, W, tgt, flags, out);
}

// Round 14
// 180.548 us; speedup vs baseline: 2.2742x; 2.2742x over previous
//
#include <hip/hip_runtime.h>
#include <math.h>

#define BB   4096
#define KK   200
#define DD   128
#define FDIM 1024
#define MASK_FILL (-4294967295.0f)   // -(2^32)+1, as fp32

typedef float fx4 __attribute__((ext_vector_type(4)));

__device__ __forceinline__ float red32(float v) {
    #pragma unroll
    for (int off = 16; off > 0; off >>= 1) v += __shfl_xor(v, off);
    return v;
}

// ---------------- Kernel 1: target = target_feats @ W^T  (R9's proven version)
__global__ __launch_bounds__(256) void target_gemm(const float* __restrict__ tf,
                                                   const float* __restrict__ W,
                                                   float* __restrict__ tgt) {
    __shared__ float s_tf[8 * FDIM];        // 32 KiB
    __shared__ float s_red[8][DD];          // 4 KiB
    const int tid = threadIdx.x;
    const int d   = tid & 127;
    const int h   = tid >> 7;               // 0/1: which half of FD (wave-uniform)
    const size_t r0 = (size_t)blockIdx.x * 8;

    const fx4* src = (const fx4*)(tf + r0 * FDIM);
    for (int i = tid; i < 8 * FDIM / 4; i += 256)
        ((fx4*)s_tf)[i] = src[i];
    __syncthreads();

    float acc[8] = {0, 0, 0, 0, 0, 0, 0, 0};
    const fx4* wr = (const fx4*)(W + (size_t)d * FDIM) + h * (FDIM / 8);
    #pragma unroll 4
    for (int i = 0; i < FDIM / 8; ++i) {
        fx4 w = wr[i];
        #pragma unroll
        for (int r = 0; r < 8; ++r) {
            fx4 t = ((const fx4*)(s_tf + r * FDIM + h * (FDIM / 2)))[i];  // wave-broadcast
            acc[r] += w.x * t.x + w.y * t.y + w.z * t.z + w.w * t.w;
        }
    }
    if (h == 1) {
        #pragma unroll
        for (int r = 0; r < 8; ++r) s_red[r][d] = acc[r];
    }
    __syncthreads();
    if (h == 0) {
        #pragma unroll
        for (int r = 0; r < 8; ++r)
            tgt[(r0 + r) * DD + d] = acc[r] + s_red[r][d];
    }
}

// ---------------- Kernel 2: TWO waves per batch row, online softmax, 1-deep
// software pipeline. Masks are PRELOADED into 2 registers and fetched per
// chunk via __shfl (DS pipe) so no mask load sits in the vmcnt FIFO — the
// R12 version's mask loads (issued after the next chunk's stream loads)
// forced every chunk to drain the pipeline (vmcnt is issue-order FIFO).
__global__ __launch_bounds__(256, 8) void attn_online(const float* __restrict__ nf,
                                                      const float* __restrict__ nl,
                                                      const int*   __restrict__ mask,
                                                      const float* __restrict__ tgt,
                                                      float* __restrict__ out) {
    __shared__ float s_m[2][2], s_s[2][2];
    __shared__ fx4   s_an[2][2][32];     // [bloc][w][col]
    __shared__ fx4   s_al[2][2][32];

    const int tid  = threadIdx.x;
    const int lane = tid & 63;
    const int l32  = lane & 31;          // fx4 column (d = 4*l32)
    const int h2   = (lane >> 5) & 1;    // parity half: 0 -> even k, 1 -> odd k
    const int bloc = tid >> 7;           // which of the block's 2 batch rows
    const int b    = __builtin_amdgcn_readfirstlane(blockIdx.x * 2 + bloc);
    const int w    = __builtin_amdgcn_readfirstlane((tid >> 6) & 1);  // k-range half

    const fx4* nf4 = (const fx4*)(nf + (size_t)b * KK * DD) + (size_t)w * 50 * 64;
    const fx4* nl4 = (const fx4*)(nl + (size_t)b * KK * DD) + (size_t)w * 50 * 64;
    const int* mb  = mask + (size_t)b * KK + w * 100;
    const fx4  tg  = ((const fx4*)(tgt + (size_t)b * DD))[l32];

    // ---- preload this wave's 100 mask values into 2 VGPRs (k = lane, 64+lane)
    const int mv0 = mb[lane];
    const int mv1 = (lane < 36) ? mb[64 + lane] : 0;

    float m = -INFINITY, s = 0.0f;
    fx4 an = {0, 0, 0, 0}, al = {0, 0, 0, 0};

#define LOADC(N0, N1, L0, L1, c)                                    \
    {                                                               \
        const int base_ = (c) * 128 + lane;                         \
        N0 = __builtin_nontemporal_load(nf4 + base_);               \
        N1 = __builtin_nontemporal_load(nf4 + base_ + 64);          \
        L0 = __builtin_nontemporal_load(nl4 + base_);               \
        L1 = __builtin_nontemporal_load(nl4 + base_ + 64);          \
    }

    // masks via shfl from mv0/mv1; (c) is compile-time after full unroll
#define COMPC(N0, N1, L0, L1, c)                                             \
    {                                                                        \
        float a0 = red32(N0.x * tg.x + N0.y * tg.y + N0.z * tg.z + N0.w * tg.w); \
        float a1 = red32(N1.x * tg.x + N1.y * tg.y + N1.z * tg.z + N1.w * tg.w); \
        const int mA_ = ((c) * 4 + 3 < 64) ? __shfl(mv0, (c) * 4 + h2)       \
                                           : __shfl(mv1, (c) * 4 - 64 + h2); \
        const int mB_ = ((c) * 4 + 3 < 64) ? __shfl(mv0, (c) * 4 + 2 + h2)   \
                                           : __shfl(mv1, (c) * 4 - 62 + h2); \
        a0 = (mA_ > 0) ? a0 : MASK_FILL;                                     \
        a1 = (mB_ > 0) ? a1 : MASK_FILL;                                     \
        const float mn_ = fmaxf(m, fmaxf(a0, a1));                           \
        const float r_  = __expf(m - mn_);                                   \
        m = mn_;                                                             \
        s *= r_; an *= r_; al *= r_;                                         \
        const float p0_ = __expf(a0 - m);                                    \
        const float p1_ = __expf(a1 - m);                                    \
        s += p0_ + p1_;                                                      \
        an += p0_ * N0 + p1_ * N1;                                           \
        al += p0_ * L0 + p1_ * L1;                                           \
    }

    fx4 nA0, nA1, lA0, lA1, nB0, nB1, lB0, lB1;
    LOADC(nA0, nA1, lA0, lA1, 0)
    #pragma unroll
    for (int c = 0; c < 24; c += 2) {
        LOADC(nB0, nB1, lB0, lB1, c + 1)
        COMPC(nA0, nA1, lA0, lA1, c)
        LOADC(nA0, nA1, lA0, lA1, c + 2)     // c <= 22 -> chunk <= 24: in range
        COMPC(nB0, nB1, lB0, lB1, c + 1)
    }
    COMPC(nA0, nA1, lA0, lA1, 24)            // last chunk, loaded in final iter

#undef LOADC
#undef COMPC

    // ---- intra-wave merge: even-k state <-> odd-k state (all lanes end up full)
    {
        const float mo = __shfl_xor(m, 32);
        const float so = __shfl_xor(s, 32);
        fx4 ano, alo;
        ano.x = __shfl_xor(an.x, 32); ano.y = __shfl_xor(an.y, 32);
        ano.z = __shfl_xor(an.z, 32); ano.w = __shfl_xor(an.w, 32);
        alo.x = __shfl_xor(al.x, 32); alo.y = __shfl_xor(al.y, 32);
        alo.z = __shfl_xor(al.z, 32); alo.w = __shfl_xor(al.w, 32);
        const float mt = fmaxf(m, mo);
        const float e0 = __expf(m - mt);
        const float e1 = __expf(mo - mt);
        s  = s * e0 + so * e1;
        an = an * e0 + ano * e1;
        al = al * e0 + alo * e1;
        m  = mt;
    }

    // ---- cross-wave merge (k-range halves) via LDS, one barrier
    if (h2 == 0) s_an[bloc][w][l32] = an; else s_al[bloc][w][l32] = al;
    if (lane == 0) { s_m[bloc][w] = m; s_s[bloc][w] = s; }
    __syncthreads();

    if (w == 0) {
        const float m1 = s_m[bloc][1];
        const float s1 = s_s[bloc][1];
        const fx4 mine  = (h2 == 0) ? an : al;
        const fx4 other = (h2 == 0) ? s_an[bloc][1][l32] : s_al[bloc][1][l32];
        const float M   = fmaxf(m, m1);
        const float e0  = __expf(m - M);
        const float e1  = __expf(m1 - M);
        const float inv = 1.0f / (s * e0 + s1 * e1);
        const fx4 r = (mine * e0 + other * e1) * inv;
        if (h2 == 0)
            __builtin_nontemporal_store(r, &((fx4*)(out + (size_t)b * DD))[l32]);
        else
            __builtin_nontemporal_store(r, &((fx4*)(out + (size_t)BB * DD + (size_t)b * DD))[l32]);
    }
}

extern "C" void kernel_launch(void* const* d_in, const int* in_sizes, int n_in,
                              void* d_out, int out_size, void* d_ws, size_t ws_size,
                              hipStream_t stream) {
    const float* tf   = (const float*)d_in[0];
    const float* nf   = (const float*)d_in[1];
    const float* nl   = (const float*)d_in[2];
    const int*   mask = (const int*)d_in[3];
    const float* W    = (const float*)d_in[4];
    float* out = (float*)d_out;
    float* tgt = (float*)d_ws;                 // B*D*4 = 2 MiB scratch

    target_gemm<<<BB / 8, 256, 0, stream>>>(tf, W, tgt);
    attn_online<<<BB / 2, 256, 0, stream>>>(nf, nl, mask, tgt, out);
}